// Round 2
// baseline (495.402 us; speedup 1.0000x reference)
//
#include <hip/hip_runtime.h>
#include <stdint.h>
#include <math.h>

#define M_DIM 8192
#define N_DIM 4096
#define K_DIM 4096
#define BITWIDTH 7

#define BM 128
#define BN 128
#define BK 64

using i32x4 = __attribute__((ext_vector_type(4))) int;

// ---------------------------------------------------------------------------
// Pack int32 (values in int8 range) -> int8, 4 elements per thread.
// ---------------------------------------------------------------------------
__global__ __launch_bounds__(256) void pack_kernel(const int* __restrict__ src,
                                                   uint32_t* __restrict__ dst,
                                                   int n4) {
    int i = blockIdx.x * blockDim.x + threadIdx.x;
    if (i >= n4) return;
    int4 v = ((const int4*)src)[i];
    uint32_t p = (uint32_t)(v.x & 0xFF)
               | ((uint32_t)(v.y & 0xFF) << 8)
               | ((uint32_t)(v.z & 0xFF) << 16)
               | ((uint32_t)(v.w & 0xFF) << 24);
    dst[i] = p;
}

// ---------------------------------------------------------------------------
// async global->LDS, 16B per lane, LDS dest = wave-uniform base + lane*16
// ---------------------------------------------------------------------------
__device__ __forceinline__ void gload_lds16(const int8_t* g, int8_t* lds) {
    __builtin_amdgcn_global_load_lds(
        (__attribute__((address_space(1))) void*)g,
        (__attribute__((address_space(3))) void*)lds,
        16, 0, 0);
}

// ---------------------------------------------------------------------------
// i8 GEMM: C[m][n] = sum_k A8[m][k] * B8[n][k]   (B given transposed)
// 128x128 block tile, BK=64, 4 waves (2x2) x 64x64 per wave,
// mfma_i32_16x16x64_i8. Writes int32 acc into C (=d_out) and atomicMax |acc|.
// ---------------------------------------------------------------------------
__global__ __launch_bounds__(256) void gemm_i8(const int8_t* __restrict__ A8,
                                               const int8_t* __restrict__ B8,
                                               int* __restrict__ C,
                                               int* __restrict__ maxabs) {
    __shared__ __align__(16) int8_t As[BM * BK];   // 8 KB
    __shared__ __align__(16) int8_t Bs[BN * BK];   // 8 KB
    __shared__ int wmaxs[4];

    const int tid  = threadIdx.x;
    const int wave = tid >> 6;
    const int lane = tid & 63;

    const int row0 = blockIdx.y * BM;
    const int col0 = blockIdx.x * BN;

    const int wm = (wave >> 1) * 64;   // wave row offset in block tile
    const int wn = (wave & 1) * 64;    // wave col offset

    i32x4 acc[4][4];
#pragma unroll
    for (int i = 0; i < 4; ++i)
#pragma unroll
        for (int j = 0; j < 4; ++j)
            acc[i][j] = (i32x4)(0);

    // staging: each wave stages 32 rows of A and 32 rows of B per K-tile,
    // two global_load_lds of 16 rows (64B/row) each.
    const int lr  = lane >> 2;          // 0..15: row within 16-row group
    const int lcb = (lane & 3) << 4;    // 0/16/32/48: byte chunk within 64B row
    const int ra  = wave * 32;

    const int8_t* ag = A8 + (size_t)(row0 + ra + lr) * K_DIM + lcb;
    const int8_t* bg = B8 + (size_t)(col0 + ra + lr) * K_DIM + lcb;

    // fragment addressing: A[m=lane&15][k=(lane>>4)*16 + j], j=0..15 bytes
    const int fr = lane & 15;
    const int fk = (lane >> 4) << 4;

    for (int k0 = 0; k0 < K_DIM; k0 += BK) {
        __syncthreads();   // protect LDS from previous iteration's readers
        gload_lds16(ag + k0,                        As + ra * BK);
        gload_lds16(ag + k0 + (size_t)16 * K_DIM,   As + (ra + 16) * BK);
        gload_lds16(bg + k0,                        Bs + ra * BK);
        gload_lds16(bg + k0 + (size_t)16 * K_DIM,   Bs + (ra + 16) * BK);
        __syncthreads();   // compiler emits s_waitcnt vmcnt(0) before barrier

        i32x4 af[4], bf[4];
#pragma unroll
        for (int i = 0; i < 4; ++i)
            af[i] = *(const i32x4*)(As + (wm + i * 16 + fr) * BK + fk);
#pragma unroll
        for (int j = 0; j < 4; ++j)
            bf[j] = *(const i32x4*)(Bs + (wn + j * 16 + fr) * BK + fk);

#pragma unroll
        for (int i = 0; i < 4; ++i)
#pragma unroll
            for (int j = 0; j < 4; ++j)
                acc[i][j] = __builtin_amdgcn_mfma_i32_16x16x64_i8(
                    af[i], bf[j], acc[i][j], 0, 0, 0);
    }

    // epilogue: C/D layout col=lane&15, row=(lane>>4)*4+reg  (dtype-independent)
    int mymax = 0;
    const int crow = (lane >> 4) << 2;
    const int ccol = lane & 15;
#pragma unroll
    for (int i = 0; i < 4; ++i) {
#pragma unroll
        for (int j = 0; j < 4; ++j) {
            int* p = C + (size_t)(row0 + wm + i * 16 + crow) * N_DIM
                       + (col0 + wn + j * 16 + ccol);
#pragma unroll
            for (int r = 0; r < 4; ++r) {
                int v = acc[i][j][r];
                p[(size_t)r * N_DIM] = v;
                int a = v < 0 ? -v : v;
                mymax = a > mymax ? a : mymax;
            }
        }
    }

    // wave-reduce max, then one atomic per block
#pragma unroll
    for (int off = 32; off > 0; off >>= 1) {
        int o = __shfl_down(mymax, off, 64);
        mymax = o > mymax ? o : mymax;
    }
    if (lane == 0) wmaxs[wave] = mymax;
    __syncthreads();
    if (tid == 0) {
        int bmx = wmaxs[0];
        for (int w = 1; w < 4; ++w) bmx = wmaxs[w] > bmx ? wmaxs[w] : bmx;
        atomicMax(maxabs, bmx);
    }
}

// ---------------------------------------------------------------------------
// Pseudo-stochastic shift, faithful to PstoShiftInt32 (all-integer, exact).
// Returns the int8 result sign-extended to int32.
// ---------------------------------------------------------------------------
__device__ __forceinline__ int psto(int x, int eff) {
    if (eff > 0) {
        int rt   = x >> eff;                 // floor divide by 2^eff
        int prob = x & ((1 << eff) - 1);     // non-negative floor remainder
        int h    = eff >> 1;
        int qp   = prob >> h;
        int prn  = (prob & ((1 << h) - 1)) << (eff & 1);
        int sgn  = (x > 0) - (x < 0);
        int r    = rt + ((qp <= prn) ? 0 : sgn);
        r = r < -127 ? -127 : r;
        r = r > 127 ? 127 : r;
        return r;
    }
    return (int)(int8_t)x;                   // wrapping int8 cast, as in torch
}

// ---------------------------------------------------------------------------
// In-place: read int32 acc from C, write int32 quantized value back.
// (d_out is an int32 buffer — harness reads np.int32 then casts to float.)
// ---------------------------------------------------------------------------
__global__ __launch_bounds__(256) void finalize_kernel(int* __restrict__ C,
        const int* __restrict__ maxabs,
        const int* __restrict__ exp_in,
        const int* __restrict__ wexp) {
    const int m = *maxabs;
    int bw = 0;
    if (m != 0) bw = (int)ceilf(log2f((float)m));   // float32 path, as reference
    const int shift = bw - BITWIDTH;
    const int eff = (shift > 1) ? shift : ((shift == 1) ? 2 : 0);

    const size_t idx = ((size_t)blockIdx.x * blockDim.x + threadIdx.x) * 4;
    int4 v = *(const int4*)(C + idx);
    int4 o;
    o.x = psto(v.x, eff);
    o.y = psto(v.y, eff);
    o.z = psto(v.z, eff);
    o.w = psto(v.w, eff);
    *(int4*)(C + idx) = o;

    if (idx == 0) {
        C[(size_t)M_DIM * N_DIM] = (int)(int8_t)(exp_in[0] + wexp[0] + eff);
    }
}

// ---------------------------------------------------------------------------
extern "C" void kernel_launch(void* const* d_in, const int* in_sizes, int n_in,
                              void* d_out, int out_size, void* d_ws, size_t ws_size,
                              hipStream_t stream) {
    const int* act    = (const int*)d_in[0];
    const int* exp_in = (const int*)d_in[1];
    const int* wt     = (const int*)d_in[2];
    const int* wexp   = (const int*)d_in[3];

    int8_t* act8   = (int8_t*)d_ws;                          // 32 MB
    int8_t* w8     = act8 + (size_t)M_DIM * K_DIM;           // 16 MB
    int*    maxabs = (int*)(w8 + (size_t)N_DIM * K_DIM);     // 4 B

    hipMemsetAsync(maxabs, 0, sizeof(int), stream);

    pack_kernel<<<(M_DIM * K_DIM / 4) / 256, 256, 0, stream>>>(
        act, (uint32_t*)act8, M_DIM * K_DIM / 4);
    pack_kernel<<<(N_DIM * K_DIM / 4) / 256, 256, 0, stream>>>(
        wt, (uint32_t*)w8, N_DIM * K_DIM / 4);

    int* C = (int*)d_out;    // acc staged in-place in d_out
    dim3 grid(N_DIM / BN, M_DIM / BM);
    gemm_i8<<<grid, 256, 0, stream>>>(act8, w8, C, maxabs);

    finalize_kernel<<<((size_t)M_DIM * N_DIM / 4) / 256, 256, 0, stream>>>(
        C, maxabs, exp_in, wexp);
}

// Round 3
// 490.567 us; speedup vs baseline: 1.0099x; 1.0099x over previous
//
#include <hip/hip_runtime.h>
#include <stdint.h>
#include <math.h>

#define M_DIM 8192
#define N_DIM 4096
#define K_DIM 4096
#define BITWIDTH 7

#define BM 128
#define BN 128
#define BK 64   // bytes of K per tile

using i32x4  = __attribute__((ext_vector_type(4)))  int;
using i32x16 = __attribute__((ext_vector_type(16))) int;

// ---------------------------------------------------------------------------
// Fused pack: int32 (int8-range values) -> int8 for BOTH tensors in one
// launch. 8 elements (32B read, 8B write) per thread. Block-aligned split:
// act = 8192*4096 elem -> 4194304 int8-packs of 8 -> blocks 0..16383;
// weight -> blocks 16384..24575. Split is uniform per block (no divergence).
// ---------------------------------------------------------------------------
__global__ __launch_bounds__(256) void pack_both_kernel(
        const int* __restrict__ act, const int* __restrict__ wt,
        uint32_t* __restrict__ act8, uint32_t* __restrict__ w8) {
    const int ACT_N8 = (M_DIM * K_DIM) / 8;   // 4194304
    int i = blockIdx.x * blockDim.x + threadIdx.x;
    const int* src;
    uint32_t* dst;
    if (i < ACT_N8) { src = act; dst = act8; }
    else            { src = wt;  dst = w8;  i -= ACT_N8; }
    int4 a = ((const int4*)src)[2 * i];
    int4 b = ((const int4*)src)[2 * i + 1];
    uint32_t p0 = (uint32_t)(a.x & 0xFF) | ((uint32_t)(a.y & 0xFF) << 8)
                | ((uint32_t)(a.z & 0xFF) << 16) | ((uint32_t)(a.w & 0xFF) << 24);
    uint32_t p1 = (uint32_t)(b.x & 0xFF) | ((uint32_t)(b.y & 0xFF) << 8)
                | ((uint32_t)(b.z & 0xFF) << 16) | ((uint32_t)(b.w & 0xFF) << 24);
    ((uint2*)dst)[i] = make_uint2(p0, p1);
}

// ---------------------------------------------------------------------------
// async global->LDS, 16B per lane, LDS dest = wave-uniform base + lane*16
// ---------------------------------------------------------------------------
__device__ __forceinline__ void gload_lds16(const int8_t* g, int8_t* lds) {
    __builtin_amdgcn_global_load_lds(
        (__attribute__((address_space(1))) void*)g,
        (__attribute__((address_space(3))) void*)lds,
        16, 0, 0);
}

// ---------------------------------------------------------------------------
// i8 GEMM: C[m][n] = sum_k A8[m][k] * B8[n][k]   (B given transposed)
// 128x128 block tile, 4 waves (2x2) each owning 64x64 as 2x2 of 32x32,
// mfma_i32_32x32x32_i8 (8 MFMA/wave/iter vs 16 with 16x16x64 — lower issue
// pressure, 32x32 pipe ~12% faster per ubench). Writes int32 acc to C
// (=d_out) and atomicMax |acc|.
// ---------------------------------------------------------------------------
__global__ __launch_bounds__(256) void gemm_i8(const int8_t* __restrict__ A8,
                                               const int8_t* __restrict__ B8,
                                               int* __restrict__ C,
                                               int* __restrict__ maxabs) {
    __shared__ __align__(16) int8_t As[BM * BK];   // 8 KB
    __shared__ __align__(16) int8_t Bs[BN * BK];   // 8 KB
    __shared__ int wmaxs[4];

    const int tid  = threadIdx.x;
    const int wave = tid >> 6;
    const int lane = tid & 63;

    const int row0 = blockIdx.y * BM;
    const int col0 = blockIdx.x * BN;

    const int wm = (wave >> 1) * 64;   // wave row offset in block tile
    const int wn = (wave & 1) * 64;    // wave col offset

    i32x16 acc[2][2];
#pragma unroll
    for (int i = 0; i < 2; ++i)
#pragma unroll
        for (int j = 0; j < 2; ++j)
            acc[i][j] = (i32x16)(0);

    // staging: each wave stages 32 rows of A and 32 rows of B per K-tile,
    // two global_load_lds of 16 rows (64B/row) each.
    const int lr  = lane >> 2;          // 0..15: row within 16-row group
    const int lcb = (lane & 3) << 4;    // 0/16/32/48: byte chunk within row
    const int ra  = wave * 32;

    const int8_t* ag = A8 + (size_t)(row0 + ra + lr) * K_DIM + lcb;
    const int8_t* bg = B8 + (size_t)(col0 + ra + lr) * K_DIM + lcb;

    // 32x32x32 i8 A/B fragment: row = lane&31, k = (lane>>5)*16 + j, j=0..15
    const int fr = lane & 31;
    const int fk = (lane >> 5) << 4;

    for (int k0 = 0; k0 < K_DIM; k0 += BK) {
        __syncthreads();   // protect LDS from previous iteration's readers
        gload_lds16(ag + k0,                        As + ra * BK);
        gload_lds16(ag + k0 + (size_t)16 * K_DIM,   As + (ra + 16) * BK);
        gload_lds16(bg + k0,                        Bs + ra * BK);
        gload_lds16(bg + k0 + (size_t)16 * K_DIM,   Bs + (ra + 16) * BK);
        __syncthreads();   // drains vmcnt(0) before barrier

        i32x4 af[2][2], bf[2][2];
#pragma unroll
        for (int i = 0; i < 2; ++i)
#pragma unroll
            for (int kk = 0; kk < 2; ++kk) {
                af[i][kk] = *(const i32x4*)(As + (wm + i * 32 + fr) * BK + kk * 32 + fk);
                bf[i][kk] = *(const i32x4*)(Bs + (wn + i * 32 + fr) * BK + kk * 32 + fk);
            }

#pragma unroll
        for (int kk = 0; kk < 2; ++kk)
#pragma unroll
            for (int i = 0; i < 2; ++i)
#pragma unroll
                for (int j = 0; j < 2; ++j)
                    acc[i][j] = __builtin_amdgcn_mfma_i32_32x32x32_i8(
                        af[i][kk], bf[j][kk], acc[i][j], 0, 0, 0);
    }

    // epilogue: 32x32 C/D layout: col = lane&31,
    // row = (reg&3) + 8*(reg>>2) + 4*(lane>>5)   [m74/m101, dtype-independent]
    int mymax = 0;
    const int ccol = lane & 31;
    const int rbase = (lane >> 5) << 2;
#pragma unroll
    for (int i = 0; i < 2; ++i) {
#pragma unroll
        for (int j = 0; j < 2; ++j) {
            int* p = C + (size_t)(row0 + wm + i * 32) * N_DIM
                       + (col0 + wn + j * 32 + ccol);
#pragma unroll
            for (int r = 0; r < 16; ++r) {
                int row = (r & 3) + 8 * (r >> 2) + rbase;
                int v = acc[i][j][r];
                p[(size_t)row * N_DIM] = v;
                int a = v < 0 ? -v : v;
                mymax = a > mymax ? a : mymax;
            }
        }
    }

    // wave-reduce max, then one atomic per block
#pragma unroll
    for (int off = 32; off > 0; off >>= 1) {
        int o = __shfl_down(mymax, off, 64);
        mymax = o > mymax ? o : mymax;
    }
    if (lane == 0) wmaxs[wave] = mymax;
    __syncthreads();
    if (tid == 0) {
        int bmx = wmaxs[0];
        for (int w = 1; w < 4; ++w) bmx = wmaxs[w] > bmx ? wmaxs[w] : bmx;
        atomicMax(maxabs, bmx);
    }
}

// ---------------------------------------------------------------------------
// Pseudo-stochastic shift, faithful to PstoShiftInt32 (all-integer, exact).
// Returns the int8 result sign-extended to int32.
// ---------------------------------------------------------------------------
__device__ __forceinline__ int psto(int x, int eff) {
    if (eff > 0) {
        int rt   = x >> eff;                 // floor divide by 2^eff
        int prob = x & ((1 << eff) - 1);     // non-negative floor remainder
        int h    = eff >> 1;
        int qp   = prob >> h;
        int prn  = (prob & ((1 << h) - 1)) << (eff & 1);
        int sgn  = (x > 0) - (x < 0);
        int r    = rt + ((qp <= prn) ? 0 : sgn);
        r = r < -127 ? -127 : r;
        r = r > 127 ? 127 : r;
        return r;
    }
    return (int)(int8_t)x;                   // wrapping int8 cast, as in torch
}

// ---------------------------------------------------------------------------
// In-place: read int32 acc from C, write int32 quantized value back.
// 8 elements (two int4) per thread. d_out is an int32 buffer.
// ---------------------------------------------------------------------------
__global__ __launch_bounds__(256) void finalize_kernel(int* __restrict__ C,
        const int* __restrict__ maxabs,
        const int* __restrict__ exp_in,
        const int* __restrict__ wexp) {
    const int m = *maxabs;
    int bw = 0;
    if (m != 0) bw = (int)ceilf(log2f((float)m));   // float32 path, as reference
    const int shift = bw - BITWIDTH;
    const int eff = (shift > 1) ? shift : ((shift == 1) ? 2 : 0);

    const size_t idx = ((size_t)blockIdx.x * blockDim.x + threadIdx.x) * 8;
    int4 v0 = *(const int4*)(C + idx);
    int4 v1 = *(const int4*)(C + idx + 4);
    int4 o0, o1;
    o0.x = psto(v0.x, eff); o0.y = psto(v0.y, eff);
    o0.z = psto(v0.z, eff); o0.w = psto(v0.w, eff);
    o1.x = psto(v1.x, eff); o1.y = psto(v1.y, eff);
    o1.z = psto(v1.z, eff); o1.w = psto(v1.w, eff);
    *(int4*)(C + idx) = o0;
    *(int4*)(C + idx + 4) = o1;

    if (idx == 0) {
        C[(size_t)M_DIM * N_DIM] = (int)(int8_t)(exp_in[0] + wexp[0] + eff);
    }
}

// ---------------------------------------------------------------------------
extern "C" void kernel_launch(void* const* d_in, const int* in_sizes, int n_in,
                              void* d_out, int out_size, void* d_ws, size_t ws_size,
                              hipStream_t stream) {
    const int* act    = (const int*)d_in[0];
    const int* exp_in = (const int*)d_in[1];
    const int* wt     = (const int*)d_in[2];
    const int* wexp   = (const int*)d_in[3];

    int8_t* act8   = (int8_t*)d_ws;                          // 32 MB
    int8_t* w8     = act8 + (size_t)M_DIM * K_DIM;           // 16 MB
    int*    maxabs = (int*)(w8 + (size_t)N_DIM * K_DIM);     // 4 B

    hipMemsetAsync(maxabs, 0, sizeof(int), stream);

    // 8 elem/thread over act (4194304 packs -> 16384 blocks) then weight
    // (2097152 packs -> 8192 blocks): 24576 blocks total, block-aligned split.
    pack_both_kernel<<<24576, 256, 0, stream>>>(
        act, wt, (uint32_t*)act8, (uint32_t*)w8);

    int* C = (int*)d_out;    // acc staged in-place in d_out
    dim3 grid(N_DIM / BN, M_DIM / BM);
    gemm_i8<<<grid, 256, 0, stream>>>(act8, w8, C, maxabs);

    finalize_kernel<<<((size_t)M_DIM * N_DIM / 8) / 256, 256, 0, stream>>>(
        C, maxabs, exp_in, wexp);
}

// Round 4
// 448.489 us; speedup vs baseline: 1.1046x; 1.0938x over previous
//
#include <hip/hip_runtime.h>
#include <stdint.h>
#include <math.h>

#define M_DIM 8192
#define N_DIM 4096
#define K_DIM 4096
#define BITWIDTH 7

#define BM 128
#define BN 128
#define BK 128   // bytes of K per tile (row stride in LDS)

using i32x4  = __attribute__((ext_vector_type(4)))  int;
using i32x16 = __attribute__((ext_vector_type(16))) int;

// ---------------------------------------------------------------------------
// Fused pack: int32 (int8-range values) -> int8 for BOTH tensors, one launch.
// 8 elements (32B read, 8B write) per thread, block-aligned split.
// Also zero-inits the maxabs scalar (replaces a memset dispatch).
// ---------------------------------------------------------------------------
__global__ __launch_bounds__(256) void pack_both_kernel(
        const int* __restrict__ act, const int* __restrict__ wt,
        uint32_t* __restrict__ act8, uint32_t* __restrict__ w8,
        int* __restrict__ maxabs) {
    if (blockIdx.x == 0 && threadIdx.x == 0) *maxabs = 0;
    const int ACT_N8 = (M_DIM * K_DIM) / 8;   // 4194304
    int i = blockIdx.x * blockDim.x + threadIdx.x;
    const int* src;
    uint32_t* dst;
    if (i < ACT_N8) { src = act; dst = act8; }
    else            { src = wt;  dst = w8;  i -= ACT_N8; }
    int4 a = ((const int4*)src)[2 * i];
    int4 b = ((const int4*)src)[2 * i + 1];
    uint32_t p0 = (uint32_t)(a.x & 0xFF) | ((uint32_t)(a.y & 0xFF) << 8)
                | ((uint32_t)(a.z & 0xFF) << 16) | ((uint32_t)(a.w & 0xFF) << 24);
    uint32_t p1 = (uint32_t)(b.x & 0xFF) | ((uint32_t)(b.y & 0xFF) << 8)
                | ((uint32_t)(b.z & 0xFF) << 16) | ((uint32_t)(b.w & 0xFF) << 24);
    ((uint2*)dst)[i] = make_uint2(p0, p1);
}

// ---------------------------------------------------------------------------
// async global->LDS, 16B per lane, LDS dest = wave-uniform base + lane*16
// ---------------------------------------------------------------------------
__device__ __forceinline__ void gload_lds16(const int8_t* g, int8_t* lds) {
    __builtin_amdgcn_global_load_lds(
        (__attribute__((address_space(1))) void*)g,
        (__attribute__((address_space(3))) void*)lds,
        16, 0, 0);
}

// ---------------------------------------------------------------------------
// i8 GEMM: C[m][n] = sum_k A8[m][k] * B8[n][k]   (B given transposed)
// 128x128 block tile, BK=128, 4 waves (2x2) each owning 64x64 as 2x2 of
// 32x32, mfma_i32_32x32x32_i8, 16 MFMA per wave per barrier.
//
// LDS layout is XOR-swizzled: 16B chunk c of row r lives at slot (c ^ (r&7)).
// Staging keeps the HW's (uniform base + lane*16) LDS dest and instead
// permutes the GLOBAL source chunk per lane; fragment reads XOR their chunk
// index with (row&7). This spreads every b128 wave-read across all 8 LDS
// bank groups (R3's unswizzled 32-row read hit only 4 groups -> 2x serialize,
// SQ_LDS_BANK_CONFLICT 5e7).
// ---------------------------------------------------------------------------
__global__ __launch_bounds__(256) void gemm_i8(const int8_t* __restrict__ A8,
                                               const int8_t* __restrict__ B8,
                                               int* __restrict__ C,
                                               int* __restrict__ maxabs) {
    __shared__ __align__(16) int8_t As[BM * BK];   // 16 KB
    __shared__ __align__(16) int8_t Bs[BN * BK];   // 16 KB
    __shared__ int wmaxs[4];

    const int tid  = threadIdx.x;
    const int wave = tid >> 6;
    const int lane = tid & 63;

    const int row0 = blockIdx.y * BM;
    const int col0 = blockIdx.x * BN;

    const int wm = (wave >> 1) * 64;   // wave row offset in block tile
    const int wn = (wave & 1) * 64;    // wave col offset

    i32x16 acc[2][2];
#pragma unroll
    for (int i = 0; i < 2; ++i)
#pragma unroll
        for (int j = 0; j < 2; ++j)
            acc[i][j] = (i32x16)(0);

    // --- staging addressing -------------------------------------------------
    // Each wave stages 32 rows (ra..ra+31) of A and of B per K-tile, as
    // 4 gload16 of 8 rows each. Lane L covers row (L>>3), global chunk
    // ((L&7) ^ (L>>3)) so that LDS slot (L&7) holds the swizzled chunk.
    const int ra     = wave * 32;
    const int rowoff = lane >> 3;                         // 0..7
    const int chk    = ((lane & 7) ^ rowoff) << 4;        // swizzled src chunk

    const int8_t* ag = A8 + (size_t)(row0 + ra + rowoff) * K_DIM + chk;
    const int8_t* bg = B8 + (size_t)(col0 + ra + rowoff) * K_DIM + chk;

    // --- fragment addressing (loop-invariant) -------------------------------
    // 32x32x32 i8 A/B fragment: row = lane&31, k-bytes = (lane>>5)*16 + j.
    // K-step kk uses bytes [kk*32, kk*32+32) -> chunk c = kk*2 + (lane>>5).
    const int fr  = lane & 31;
    const int hl  = lane >> 5;
    const int swz = fr & 7;
    // per-kk LDS byte offsets within a 32-row panel
    int aoff[2][4], boff[2][4];
#pragma unroll
    for (int kk = 0; kk < 4; ++kk) {
        int c = kk * 2 + hl;
        int co = ((c ^ swz) << 4);
#pragma unroll
        for (int i = 0; i < 2; ++i) {
            aoff[i][kk] = (wm + i * 32 + fr) * BK + co;
            boff[i][kk] = (wn + i * 32 + fr) * BK + co;
        }
    }

    for (int k0 = 0; k0 < K_DIM; k0 += BK) {
        __syncthreads();   // protect LDS from previous iteration's readers
#pragma unroll
        for (int g = 0; g < 4; ++g) {
            gload_lds16(ag + k0 + (size_t)(8 * g) * K_DIM, As + (ra + 8 * g) * BK);
            gload_lds16(bg + k0 + (size_t)(8 * g) * K_DIM, Bs + (ra + 8 * g) * BK);
        }
        __syncthreads();   // drains vmcnt(0) before barrier

#pragma unroll
        for (int kk = 0; kk < 4; ++kk) {
            i32x4 af[2], bf[2];
#pragma unroll
            for (int i = 0; i < 2; ++i) {
                af[i] = *(const i32x4*)(As + aoff[i][kk]);
                bf[i] = *(const i32x4*)(Bs + boff[i][kk]);
            }
#pragma unroll
            for (int i = 0; i < 2; ++i)
#pragma unroll
                for (int j = 0; j < 2; ++j)
                    acc[i][j] = __builtin_amdgcn_mfma_i32_32x32x32_i8(
                        af[i], bf[j], acc[i][j], 0, 0, 0);
        }
    }

    // epilogue: 32x32 C/D layout: col = lane&31,
    // row = (reg&3) + 8*(reg>>2) + 4*(lane>>5)   [m74/m101, dtype-independent]
    int mymax = 0;
    const int ccol = lane & 31;
    const int rbase = hl << 2;
#pragma unroll
    for (int i = 0; i < 2; ++i) {
#pragma unroll
        for (int j = 0; j < 2; ++j) {
            int* p = C + (size_t)(row0 + wm + i * 32) * N_DIM
                       + (col0 + wn + j * 32 + ccol);
#pragma unroll
            for (int r = 0; r < 16; ++r) {
                int row = (r & 3) + 8 * (r >> 2) + rbase;
                int v = acc[i][j][r];
                p[(size_t)row * N_DIM] = v;
                int a = v < 0 ? -v : v;
                mymax = a > mymax ? a : mymax;
            }
        }
    }

    // wave-reduce max, then one atomic per block
#pragma unroll
    for (int off = 32; off > 0; off >>= 1) {
        int o = __shfl_down(mymax, off, 64);
        mymax = o > mymax ? o : mymax;
    }
    if (lane == 0) wmaxs[wave] = mymax;
    __syncthreads();
    if (tid == 0) {
        int bmx = wmaxs[0];
        for (int w = 1; w < 4; ++w) bmx = wmaxs[w] > bmx ? wmaxs[w] : bmx;
        atomicMax(maxabs, bmx);
    }
}

// ---------------------------------------------------------------------------
// Pseudo-stochastic shift, faithful to PstoShiftInt32 (all-integer, exact).
// Returns the int8 result sign-extended to int32.
// ---------------------------------------------------------------------------
__device__ __forceinline__ int psto(int x, int eff) {
    if (eff > 0) {
        int rt   = x >> eff;                 // floor divide by 2^eff
        int prob = x & ((1 << eff) - 1);     // non-negative floor remainder
        int h    = eff >> 1;
        int qp   = prob >> h;
        int prn  = (prob & ((1 << h) - 1)) << (eff & 1);
        int sgn  = (x > 0) - (x < 0);
        int r    = rt + ((qp <= prn) ? 0 : sgn);
        r = r < -127 ? -127 : r;
        r = r > 127 ? 127 : r;
        return r;
    }
    return (int)(int8_t)x;                   // wrapping int8 cast, as in torch
}

// ---------------------------------------------------------------------------
// In-place: read int32 acc from C, write int32 quantized value back.
// 8 elements (two int4) per thread. d_out is an int32 buffer.
// ---------------------------------------------------------------------------
__global__ __launch_bounds__(256) void finalize_kernel(int* __restrict__ C,
        const int* __restrict__ maxabs,
        const int* __restrict__ exp_in,
        const int* __restrict__ wexp) {
    const int m = *maxabs;
    int bw = 0;
    if (m != 0) bw = (int)ceilf(log2f((float)m));   // float32 path, as reference
    const int shift = bw - BITWIDTH;
    const int eff = (shift > 1) ? shift : ((shift == 1) ? 2 : 0);

    const size_t idx = ((size_t)blockIdx.x * blockDim.x + threadIdx.x) * 8;
    int4 v0 = *(const int4*)(C + idx);
    int4 v1 = *(const int4*)(C + idx + 4);
    int4 o0, o1;
    o0.x = psto(v0.x, eff); o0.y = psto(v0.y, eff);
    o0.z = psto(v0.z, eff); o0.w = psto(v0.w, eff);
    o1.x = psto(v1.x, eff); o1.y = psto(v1.y, eff);
    o1.z = psto(v1.z, eff); o1.w = psto(v1.w, eff);
    *(int4*)(C + idx) = o0;
    *(int4*)(C + idx + 4) = o1;

    if (idx == 0) {
        C[(size_t)M_DIM * N_DIM] = (int)(int8_t)(exp_in[0] + wexp[0] + eff);
    }
}

// ---------------------------------------------------------------------------
extern "C" void kernel_launch(void* const* d_in, const int* in_sizes, int n_in,
                              void* d_out, int out_size, void* d_ws, size_t ws_size,
                              hipStream_t stream) {
    const int* act    = (const int*)d_in[0];
    const int* exp_in = (const int*)d_in[1];
    const int* wt     = (const int*)d_in[2];
    const int* wexp   = (const int*)d_in[3];

    int8_t* act8   = (int8_t*)d_ws;                          // 32 MB
    int8_t* w8     = act8 + (size_t)M_DIM * K_DIM;           // 16 MB
    int*    maxabs = (int*)(w8 + (size_t)N_DIM * K_DIM);     // 4 B

    // 8 elem/thread over act (16384 blocks) then weight (8192 blocks).
    pack_both_kernel<<<24576, 256, 0, stream>>>(
        act, wt, (uint32_t*)act8, (uint32_t*)w8, maxabs);

    int* C = (int*)d_out;    // acc staged in-place in d_out
    dim3 grid(N_DIM / BN, M_DIM / BM);
    gemm_i8<<<grid, 256, 0, stream>>>(act8, w8, C, maxabs);

    finalize_kernel<<<((size_t)M_DIM * N_DIM / 8) / 256, 256, 0, stream>>>(
        C, maxabs, exp_in, wexp);
}

// Round 5
// 445.548 us; speedup vs baseline: 1.1119x; 1.0066x over previous
//
#include <hip/hip_runtime.h>
#include <stdint.h>
#include <math.h>

#define M_DIM 8192
#define N_DIM 4096
#define K_DIM 4096
#define BITWIDTH 7

#define BM 256
#define BN 128
#define BK 128   // bytes of K per tile (row stride in LDS)

using i32x4  = __attribute__((ext_vector_type(4)))  int;
using i32x16 = __attribute__((ext_vector_type(16))) int;

// ---------------------------------------------------------------------------
// Fused pack: int32 (int8-range values) -> int8 for BOTH tensors, one launch.
// 8 elements (32B read, 8B write) per thread, block-aligned split.
// Also zero-inits the maxabs scalar (replaces a memset dispatch).
// ---------------------------------------------------------------------------
__global__ __launch_bounds__(256) void pack_both_kernel(
        const int* __restrict__ act, const int* __restrict__ wt,
        uint32_t* __restrict__ act8, uint32_t* __restrict__ w8,
        int* __restrict__ maxabs) {
    if (blockIdx.x == 0 && threadIdx.x == 0) *maxabs = 0;
    const int ACT_N8 = (M_DIM * K_DIM) / 8;   // 4194304
    int i = blockIdx.x * blockDim.x + threadIdx.x;
    const int* src;
    uint32_t* dst;
    if (i < ACT_N8) { src = act; dst = act8; }
    else            { src = wt;  dst = w8;  i -= ACT_N8; }
    int4 a = ((const int4*)src)[2 * i];
    int4 b = ((const int4*)src)[2 * i + 1];
    uint32_t p0 = (uint32_t)(a.x & 0xFF) | ((uint32_t)(a.y & 0xFF) << 8)
                | ((uint32_t)(a.z & 0xFF) << 16) | ((uint32_t)(a.w & 0xFF) << 24);
    uint32_t p1 = (uint32_t)(b.x & 0xFF) | ((uint32_t)(b.y & 0xFF) << 8)
                | ((uint32_t)(b.z & 0xFF) << 16) | ((uint32_t)(b.w & 0xFF) << 24);
    ((uint2*)dst)[i] = make_uint2(p0, p1);
}

// ---------------------------------------------------------------------------
// async global->LDS, 16B per lane, LDS dest = wave-uniform base + lane*16
// ---------------------------------------------------------------------------
__device__ __forceinline__ void gload_lds16(const int8_t* g, int8_t* lds) {
    __builtin_amdgcn_global_load_lds(
        (__attribute__((address_space(1))) void*)g,
        (__attribute__((address_space(3))) void*)lds,
        16, 0, 0);
}

// ---------------------------------------------------------------------------
// i8 GEMM: C[m][n] = sum_k A8[m][k] * B8[n][k]   (B given transposed)
// 256x128 block tile, BK=128, 4 waves (2x2) each owning a 128x64 wave tile
// as 4x2 of 32x32, mfma_i32_32x32x32_i8: 32 MFMA per wave per barrier,
// 24 ds_read_b128 per wave per iter (0.75 reads/MFMA vs 1.0 with 64x64 —
// LDS read BW is the limiting pipe at MfmaUtil ~40%).
//
// LDS XOR swizzle (R4): 16B chunk c of row r lives at slot (c ^ (r&7));
// staging permutes the GLOBAL source chunk per lane, fragment reads XOR
// their chunk index with (row&7) -> balanced across all 8 bank groups.
// ---------------------------------------------------------------------------
__global__ __launch_bounds__(256, 2) void gemm_i8(
        const int8_t* __restrict__ A8, const int8_t* __restrict__ B8,
        int* __restrict__ C, int* __restrict__ maxabs) {
    __shared__ __align__(16) int8_t As[BM * BK];   // 32 KB
    __shared__ __align__(16) int8_t Bs[BN * BK];   // 16 KB
    __shared__ int wmaxs[4];

    const int tid  = threadIdx.x;
    const int wave = tid >> 6;
    const int lane = tid & 63;

    const int row0 = blockIdx.y * BM;
    const int col0 = blockIdx.x * BN;

    const int wm = (wave >> 1) * 128;  // wave row offset in block tile
    const int wn = (wave & 1) * 64;    // wave col offset

    i32x16 acc[4][2];
#pragma unroll
    for (int i = 0; i < 4; ++i)
#pragma unroll
        for (int j = 0; j < 2; ++j)
            acc[i][j] = (i32x16)(0);

    // --- staging addressing -------------------------------------------------
    // Per K-tile each wave stages 64 rows of A (8 gloads of 8 rows) and
    // 32 rows of B (4 gloads). Lane L covers row (L>>3), global chunk
    // ((L&7) ^ (L>>3)) so LDS slot (L&7) holds the swizzled chunk.
    const int raA    = wave * 64;
    const int raB    = wave * 32;
    const int rowoff = lane >> 3;                         // 0..7
    const int chk    = ((lane & 7) ^ rowoff) << 4;        // swizzled src chunk

    const int8_t* ag = A8 + (size_t)(row0 + raA + rowoff) * K_DIM + chk;
    const int8_t* bg = B8 + (size_t)(col0 + raB + rowoff) * K_DIM + chk;

    // --- fragment addressing (loop-invariant) -------------------------------
    // 32x32x32 i8 A/B fragment: row = lane&31, k-bytes = (lane>>5)*16 + j.
    // K-step kk uses chunk c = kk*2 + (lane>>5), LDS slot = c ^ (row&7).
    const int fr  = lane & 31;
    const int hl  = lane >> 5;
    const int swz = fr & 7;
    int aoff[4][4], boff[2][4];
#pragma unroll
    for (int kk = 0; kk < 4; ++kk) {
        int co = (((kk * 2 + hl) ^ swz) << 4);
#pragma unroll
        for (int i = 0; i < 4; ++i)
            aoff[i][kk] = (wm + i * 32 + fr) * BK + co;
#pragma unroll
        for (int j = 0; j < 2; ++j)
            boff[j][kk] = (wn + j * 32 + fr) * BK + co;
    }

    for (int k0 = 0; k0 < K_DIM; k0 += BK) {
        __syncthreads();   // protect LDS from previous iteration's readers
#pragma unroll
        for (int g = 0; g < 8; ++g)
            gload_lds16(ag + k0 + (size_t)(8 * g) * K_DIM, As + (raA + 8 * g) * BK);
#pragma unroll
        for (int g = 0; g < 4; ++g)
            gload_lds16(bg + k0 + (size_t)(8 * g) * K_DIM, Bs + (raB + 8 * g) * BK);
        __syncthreads();   // drains vmcnt(0) before barrier

#pragma unroll
        for (int kk = 0; kk < 4; ++kk) {
            i32x4 af[4], bf[2];
#pragma unroll
            for (int i = 0; i < 4; ++i)
                af[i] = *(const i32x4*)(As + aoff[i][kk]);
#pragma unroll
            for (int j = 0; j < 2; ++j)
                bf[j] = *(const i32x4*)(Bs + boff[j][kk]);
#pragma unroll
            for (int i = 0; i < 4; ++i)
#pragma unroll
                for (int j = 0; j < 2; ++j)
                    acc[i][j] = __builtin_amdgcn_mfma_i32_32x32x32_i8(
                        af[i], bf[j], acc[i][j], 0, 0, 0);
        }
    }

    // epilogue: 32x32 C/D layout: col = lane&31,
    // row = (reg&3) + 8*(reg>>2) + 4*(lane>>5)   [m74/m101, dtype-independent]
    int mymax = 0;
    const int ccol = lane & 31;
    const int rbase = hl << 2;
#pragma unroll
    for (int i = 0; i < 4; ++i) {
#pragma unroll
        for (int j = 0; j < 2; ++j) {
            int* p = C + (size_t)(row0 + wm + i * 32) * N_DIM
                       + (col0 + wn + j * 32 + ccol);
#pragma unroll
            for (int r = 0; r < 16; ++r) {
                int row = (r & 3) + 8 * (r >> 2) + rbase;
                int v = acc[i][j][r];
                p[(size_t)row * N_DIM] = v;
                int a = v < 0 ? -v : v;
                mymax = a > mymax ? a : mymax;
            }
        }
    }

    // wave-reduce max, then one atomic per block
#pragma unroll
    for (int off = 32; off > 0; off >>= 1) {
        int o = __shfl_down(mymax, off, 64);
        mymax = o > mymax ? o : mymax;
    }
    if (lane == 0) wmaxs[wave] = mymax;
    __syncthreads();
    if (tid == 0) {
        int bmx = wmaxs[0];
        for (int w = 1; w < 4; ++w) bmx = wmaxs[w] > bmx ? wmaxs[w] : bmx;
        atomicMax(maxabs, bmx);
    }
}

// ---------------------------------------------------------------------------
// Pseudo-stochastic shift, faithful to PstoShiftInt32 (all-integer, exact).
// Returns the int8 result sign-extended to int32.
// ---------------------------------------------------------------------------
__device__ __forceinline__ int psto(int x, int eff) {
    if (eff > 0) {
        int rt   = x >> eff;                 // floor divide by 2^eff
        int prob = x & ((1 << eff) - 1);     // non-negative floor remainder
        int h    = eff >> 1;
        int qp   = prob >> h;
        int prn  = (prob & ((1 << h) - 1)) << (eff & 1);
        int sgn  = (x > 0) - (x < 0);
        int r    = rt + ((qp <= prn) ? 0 : sgn);
        r = r < -127 ? -127 : r;
        r = r > 127 ? 127 : r;
        return r;
    }
    return (int)(int8_t)x;                   // wrapping int8 cast, as in torch
}

// ---------------------------------------------------------------------------
// In-place: read int32 acc from C, write int32 quantized value back.
// 8 elements (two int4) per thread. d_out is an int32 buffer.
// ---------------------------------------------------------------------------
__global__ __launch_bounds__(256) void finalize_kernel(int* __restrict__ C,
        const int* __restrict__ maxabs,
        const int* __restrict__ exp_in,
        const int* __restrict__ wexp) {
    const int m = *maxabs;
    int bw = 0;
    if (m != 0) bw = (int)ceilf(log2f((float)m));   // float32 path, as reference
    const int shift = bw - BITWIDTH;
    const int eff = (shift > 1) ? shift : ((shift == 1) ? 2 : 0);

    const size_t idx = ((size_t)blockIdx.x * blockDim.x + threadIdx.x) * 8;
    int4 v0 = *(const int4*)(C + idx);
    int4 v1 = *(const int4*)(C + idx + 4);
    int4 o0, o1;
    o0.x = psto(v0.x, eff); o0.y = psto(v0.y, eff);
    o0.z = psto(v0.z, eff); o0.w = psto(v0.w, eff);
    o1.x = psto(v1.x, eff); o1.y = psto(v1.y, eff);
    o1.z = psto(v1.z, eff); o1.w = psto(v1.w, eff);
    *(int4*)(C + idx) = o0;
    *(int4*)(C + idx + 4) = o1;

    if (idx == 0) {
        C[(size_t)M_DIM * N_DIM] = (int)(int8_t)(exp_in[0] + wexp[0] + eff);
    }
}

// ---------------------------------------------------------------------------
extern "C" void kernel_launch(void* const* d_in, const int* in_sizes, int n_in,
                              void* d_out, int out_size, void* d_ws, size_t ws_size,
                              hipStream_t stream) {
    const int* act    = (const int*)d_in[0];
    const int* exp_in = (const int*)d_in[1];
    const int* wt     = (const int*)d_in[2];
    const int* wexp   = (const int*)d_in[3];

    int8_t* act8   = (int8_t*)d_ws;                          // 32 MB
    int8_t* w8     = act8 + (size_t)M_DIM * K_DIM;           // 16 MB
    int*    maxabs = (int*)(w8 + (size_t)N_DIM * K_DIM);     // 4 B

    // 8 elem/thread over act (16384 blocks) then weight (8192 blocks).
    pack_both_kernel<<<24576, 256, 0, stream>>>(
        act, wt, (uint32_t*)act8, (uint32_t*)w8, maxabs);

    int* C = (int*)d_out;    // acc staged in-place in d_out
    dim3 grid(N_DIM / BN, M_DIM / BM);
    gemm_i8<<<grid, 256, 0, stream>>>(act8, w8, C, maxabs);

    finalize_kernel<<<((size_t)M_DIM * N_DIM / 8) / 256, 256, 0, stream>>>(
        C, maxabs, exp_in, wexp);
}